// Round 4
// baseline (471.194 us; speedup 1.0000x reference)
//
#include <hip/hip_runtime.h>
#include <stdint.h>

// Problem constants: B=4, T=4096, D=1024
#define D_DIM 1024
#define T_DIM 4096
#define B_DIM 4
#define M_DIM (B_DIM * T_DIM)   // 16384 rows
#define NCH 64                  // scan chunks
#define CHL 64                  // chunk length

typedef short bf16x8 __attribute__((ext_vector_type(8)));
typedef float f32x4 __attribute__((ext_vector_type(4)));

__device__ __forceinline__ ushort f2bf(float f) {
    union { float f; uint32_t u; } x; x.f = f;
    uint32_t r = x.u + 0x7fffu + ((x.u >> 16) & 1u);   // RNE
    return (ushort)(r >> 16);
}
__device__ __forceinline__ float bf2f(ushort u) {
    union { uint32_t u; float f; } x; x.u = (uint32_t)u << 16; return x.f;
}

__device__ __forceinline__ void gload16(const ushort* g, ushort* l) {
    __builtin_amdgcn_global_load_lds(
        (const __attribute__((address_space(1))) void*)g,
        (__attribute__((address_space(3))) void*)l, 16, 0, 0);
}

// ---------------- weight fp32 -> bf16 (Wk,Wv,Wr,Wo concatenated) -------------
__global__ void convw(const float* __restrict__ w0, const float* __restrict__ w1,
                      const float* __restrict__ w2, const float* __restrict__ w3,
                      ushort* __restrict__ out) {
    int i = blockIdx.x * 256 + threadIdx.x;        // 1M float4 groups
    int sel = i >> 18;
    const float* src = sel == 0 ? w0 : sel == 1 ? w1 : sel == 2 ? w2 : w3;
    int off = (i & 0x3ffff) << 2;
    float4 f = *(const float4*)(src + off);
    ushort4 o; o.x = f2bf(f.x); o.y = f2bf(f.y); o.z = f2bf(f.z); o.w = f2bf(f.w);
    *(ushort4*)(out + (size_t)i * 4) = o;
}

// ---------------- token shift + time-mix (one mix vector) -> bf16 ------------
__global__ void mixz(const float* __restrict__ x, const float* __restrict__ tm,
                     ushort* __restrict__ o) {
    size_t gid = (size_t)blockIdx.x * 256 + threadIdx.x;
    size_t e = gid * 4;
    int d = (int)(e & (D_DIM - 1));
    int t = (int)((e >> 10) & (T_DIM - 1));
    float4 xc = *(const float4*)(x + e);
    float4 xp = make_float4(0.f, 0.f, 0.f, 0.f);
    if (t > 0) xp = *(const float4*)(x + e - D_DIM);
    float4 m = *(const float4*)(tm + d);
    ushort4 r;
    r.x = f2bf(xc.x * m.x + xp.x * (1.f - m.x));
    r.y = f2bf(xc.y * m.y + xp.y * (1.f - m.y));
    r.z = f2bf(xc.z * m.z + xp.z * (1.f - m.z));
    r.w = f2bf(xc.w * m.w + xp.w * (1.f - m.w));
    *(ushort4*)(o + e) = r;
}

// ---------------- bf16 GEMM: C[M,N] = A[M,K] * B[N,K]^T ----------------------
// OUTF32 = 0 -> bf16 C; OUTF32 = 1 -> f32 C (final output GEMM)
template <int OUTF32>
__global__ void __launch_bounds__(256)
gemm_bt(const ushort* __restrict__ A, const ushort* __restrict__ Bw,
        void* __restrict__ Cv) {
    constexpr int K = 1024, N = 1024;
    __shared__ ushort As[128 * 32];
    __shared__ ushort Bs[128 * 32];
    const int tid = threadIdx.x;
    const int wid = tid >> 6, lane = tid & 63;
    const int wr = wid >> 1, wc = wid & 1;

    const ushort* Ab = A + (size_t)blockIdx.y * 128 * K;
    const ushort* Bb = Bw + (size_t)blockIdx.x * 128 * K;
    const ushort* ga = Ab + (size_t)(tid >> 2) * K + ((tid & 3) << 3);
    const ushort* gb = Bb + (size_t)(tid >> 2) * K + ((tid & 3) << 3);
    ushort* lA0 = &As[wid * 512];
    ushort* lA1 = &As[2048 + wid * 512];
    ushort* lB0 = &Bs[wid * 512];
    ushort* lB1 = &Bs[2048 + wid * 512];
    const size_t rstep = (size_t)64 * K;

    f32x4 acc[4][4] = {};
    const int frow = lane & 15;
    const int kgrp = (lane >> 4) << 3;

    for (int kt = 0; kt < K; kt += 32) {
        __syncthreads();                  // previous tile fully consumed
        gload16(ga + kt, lA0);
        gload16(ga + kt + rstep, lA1);
        gload16(gb + kt, lB0);
        gload16(gb + kt + rstep, lB1);
        __syncthreads();                  // compiler drains vmcnt before barrier
        bf16x8 af[4], bfr[4];
#pragma unroll
        for (int m = 0; m < 4; ++m)
            af[m] = *(const bf16x8*)&As[(wr * 64 + m * 16 + frow) * 32 + kgrp];
#pragma unroll
        for (int n = 0; n < 4; ++n)
            bfr[n] = *(const bf16x8*)&Bs[(wc * 64 + n * 16 + frow) * 32 + kgrp];
#pragma unroll
        for (int m = 0; m < 4; ++m)
#pragma unroll
            for (int n = 0; n < 4; ++n)
                acc[m][n] = __builtin_amdgcn_mfma_f32_16x16x32_bf16(
                    af[m], bfr[n], acc[m][n], 0, 0, 0);
    }

    // C/D layout: col = lane&15, row = (lane>>4)*4 + reg  [m89/m91]
    const int rsub = (lane >> 4) << 2;
    const int col = blockIdx.x * 128 + wc * 64 + frow;
    const int row0 = blockIdx.y * 128 + wr * 64 + rsub;
#pragma unroll
    for (int m = 0; m < 4; ++m)
#pragma unroll
        for (int n = 0; n < 4; ++n)
#pragma unroll
            for (int r = 0; r < 4; ++r) {
                size_t idx = (size_t)(row0 + m * 16 + r) * N + col + n * 16;
                if (OUTF32)
                    ((float*)Cv)[idx] = acc[m][n][r];
                else
                    ((ushort*)Cv)[idx] = f2bf(acc[m][n][r]);
            }
}

// ---------------- WKV blocked scan (bf16 k,v,r) ------------------------------
// Per-chunk summary: m_c = max_i(k_i+(L-1-i)w), s_c = sum_i e^{k_i+(L-1-i)w-m_c} v_i
__global__ void wkv_passA(const ushort* __restrict__ k, const ushort* __restrict__ v,
                          const float* __restrict__ w_, float* __restrict__ m_arr,
                          float* __restrict__ s_arr) {
    int gid = blockIdx.x * 256 + threadIdx.x;   // (c*B+b)*D + d  -> 262144
    int d = gid & 1023;
    int b = (gid >> 10) & 3;
    int c = gid >> 12;
    float w = w_[d];
    size_t base = ((size_t)(b * T_DIM + c * CHL)) * D_DIM + d;
    float m = -1e30f, s = 0.f;
#pragma unroll 4
    for (int i = 0; i < CHL; ++i) {
        float kk = bf2f(k[base + (size_t)i * D_DIM]);
        float vv = bf2f(v[base + (size_t)i * D_DIM]);
        float e = kk + (float)(CHL - 1 - i) * w;
        float nm = fmaxf(m, e);
        s = s * __expf(fmaxf(m - nm, -30.f)) + __expf(fmaxf(e - nm, -30.f)) * vv;
        m = nm;
    }
    m_arr[gid] = m;
    s_arr[gid] = s;
}

__global__ void wkv_passB(const float* __restrict__ m_arr, const float* __restrict__ s_arr,
                          const float* __restrict__ w_, float* __restrict__ pin,
                          float* __restrict__ qin) {
    int gid = blockIdx.x * 256 + threadIdx.x;   // b*D + d -> 4096
    int d = gid & 1023;
    int b = gid >> 10;
    float w = w_[d];
    float Lw = (float)CHL * w;
    float p = -1e30f, q = 0.f;
    for (int c = 0; c < NCH; ++c) {
        int idx = ((c * B_DIM + b) << 10) | d;
        pin[idx] = p; qin[idx] = q;
        float mc = m_arr[idx], sc = s_arr[idx];
        float pn = fmaxf(p + Lw, mc);
        q = __expf(fmaxf(p + Lw - pn, -30.f)) * q +
            __expf(fmaxf(mc - pn, -30.f)) * sc;
        p = pn;
    }
}

// Pass C: exact reference step formulas from each chunk's incoming state,
// fused with sigmoid(r)*wkv and bf16 store of y.
__global__ void wkv_passC(const ushort* __restrict__ k, const ushort* __restrict__ v,
                          const ushort* __restrict__ r, const float* __restrict__ w_,
                          const float* __restrict__ u_, const float* __restrict__ pin,
                          const float* __restrict__ qin, ushort* __restrict__ y) {
    int gid = blockIdx.x * 256 + threadIdx.x;   // (c*B+b)*D + d
    int d = gid & 1023;
    int b = (gid >> 10) & 3;
    int c = gid >> 12;
    float w = w_[d], u = u_[d];
    float p = pin[gid], q = qin[gid];
    size_t base = ((size_t)(b * T_DIM + c * CHL)) * D_DIM + d;
#pragma unroll 4
    for (int i = 0; i < CHL; ++i) {
        float kk = bf2f(k[base]), vv = bf2f(v[base]), rr = bf2f(r[base]);
        float uk = u + kk;
        float np = fmaxf(p, uk);
        float so = __expf(fmaxf(p - np, -30.f));
        float sc = __expf(fmaxf(uk - np, -30.f));
        float wkv = (so * q + sc * vv) / (so + sc + 1e-9f);
        float np2 = fmaxf(p + w, kk);
        float sp = __expf(fmaxf(p + w - np2, -30.f));
        float sn = __expf(fmaxf(kk - np2, -30.f));
        q = sp * q + sn * vv;
        p = np2;
        float sig = 1.f / (1.f + __expf(-rr));
        y[base] = f2bf(sig * wkv);
        base += D_DIM;
    }
}

// ---------------- launch -----------------------------------------------------
extern "C" void kernel_launch(void* const* d_in, const int* in_sizes, int n_in,
                              void* d_out, int out_size, void* d_ws, size_t ws_size,
                              hipStream_t stream) {
    (void)in_sizes; (void)n_in; (void)out_size;
    const float* x  = (const float*)d_in[0];
    const float* mk = (const float*)d_in[1];
    const float* mv = (const float*)d_in[2];
    const float* mr = (const float*)d_in[3];
    const float* Wk = (const float*)d_in[4];
    const float* Wv = (const float*)d_in[5];
    const float* Wr = (const float*)d_in[6];
    const float* Wo = (const float*)d_in[7];
    const float* td = (const float*)d_in[8];
    const float* tf = (const float*)d_in[9];

    const size_t MD = (size_t)M_DIM * D_DIM;         // 16,777,216
    const size_t DD = (size_t)D_DIM * D_DIM;         // 1,048,576
    const size_t CHN = (size_t)B_DIM * D_DIM * NCH;  // 262,144

    // workspace layout: 140 MiB total (known-safe from round 2)
    ushort* wcat = (ushort*)d_ws;          // [4*DD] bf16 Wk,Wv,Wr,Wo
    ushort* kbuf = wcat + 4 * DD;          // [MD] bf16 k
    ushort* vbuf = kbuf + MD;              // [MD] bf16 v
    ushort* rbuf = vbuf + MD;              // [MD] bf16 r (pre-sigmoid)
    ushort* xbuf = rbuf + MD;              // [MD] bf16 mix staging, later y
    float* m_arr = (float*)(xbuf + MD);    // [CHN]
    float* s_arr = m_arr + CHN;            // [CHN]
    float* pin   = s_arr + CHN;            // [CHN]
    float* qin   = pin + CHN;              // [CHN]
    size_t need = (size_t)((char*)(qin + CHN) - (char*)d_ws);
    if (ws_size < need) return;  // diagnostic: zero out -> absmax == max|ref| == 2.234

    dim3 ggrid(8, 128, 1);

    convw<<<4096, 256, 0, stream>>>(Wk, Wv, Wr, Wo, wcat);

    mixz<<<16384, 256, 0, stream>>>(x, mk, xbuf);
    gemm_bt<0><<<ggrid, 256, 0, stream>>>(xbuf, wcat, kbuf);
    mixz<<<16384, 256, 0, stream>>>(x, mv, xbuf);
    gemm_bt<0><<<ggrid, 256, 0, stream>>>(xbuf, wcat + DD, vbuf);
    mixz<<<16384, 256, 0, stream>>>(x, mr, xbuf);
    gemm_bt<0><<<ggrid, 256, 0, stream>>>(xbuf, wcat + 2 * DD, rbuf);

    wkv_passA<<<1024, 256, 0, stream>>>(kbuf, vbuf, td, m_arr, s_arr);
    wkv_passB<<<16, 256, 0, stream>>>(m_arr, s_arr, td, pin, qin);
    wkv_passC<<<1024, 256, 0, stream>>>(kbuf, vbuf, rbuf, td, tf, pin, qin, xbuf);

    gemm_bt<1><<<ggrid, 256, 0, stream>>>(xbuf, wcat + 3 * DD, d_out);
}

// Round 5
// 445.436 us; speedup vs baseline: 1.0578x; 1.0578x over previous
//
#include <hip/hip_runtime.h>
#include <stdint.h>

// Problem constants: B=4, T=4096, D=1024
#define D_DIM 1024
#define T_DIM 4096
#define B_DIM 4
#define M_DIM (B_DIM * T_DIM)   // 16384 rows
#define NCH 64                  // scan chunks
#define CHL 64                  // chunk length
#define GEMM_N 1024
#define GEMM_K 1024

typedef short bf16x8 __attribute__((ext_vector_type(8)));
typedef float f32x4 __attribute__((ext_vector_type(4)));

__device__ __forceinline__ ushort f2bf(float f) {
    union { float f; uint32_t u; } x; x.f = f;
    uint32_t r = x.u + 0x7fffu + ((x.u >> 16) & 1u);   // RNE
    return (ushort)(r >> 16);
}
__device__ __forceinline__ float bf2f(ushort u) {
    union { uint32_t u; float f; } x; x.u = (uint32_t)u << 16; return x.f;
}

__device__ __forceinline__ void gload16(const ushort* g, ushort* l) {
    __builtin_amdgcn_global_load_lds(
        (const __attribute__((address_space(1))) void*)g,
        (__attribute__((address_space(3))) void*)l, 16, 0, 0);
}

// ---------------- weight fp32 -> bf16 (Wk,Wv,Wr,Wo concatenated) -------------
__global__ void convw(const float* __restrict__ w0, const float* __restrict__ w1,
                      const float* __restrict__ w2, const float* __restrict__ w3,
                      ushort* __restrict__ out) {
    int i = blockIdx.x * 256 + threadIdx.x;        // 1M float4 groups
    int sel = i >> 18;
    const float* src = sel == 0 ? w0 : sel == 1 ? w1 : sel == 2 ? w2 : w3;
    int off = (i & 0x3ffff) << 2;
    float4 f = *(const float4*)(src + off);
    ushort4 o; o.x = f2bf(f.x); o.y = f2bf(f.y); o.z = f2bf(f.z); o.w = f2bf(f.w);
    *(ushort4*)(out + (size_t)i * 4) = o;
}

// ---------------- token shift + time-mix -------------------------------------
__global__ void mixz(const float* __restrict__ x, const float* __restrict__ tm,
                     ushort* __restrict__ o) {
    size_t gid = (size_t)blockIdx.x * 256 + threadIdx.x;
    size_t e = gid * 4;
    int d = (int)(e & (D_DIM - 1));
    int t = (int)((e >> 10) & (T_DIM - 1));
    float4 xc = *(const float4*)(x + e);
    float4 xp = make_float4(0.f, 0.f, 0.f, 0.f);
    if (t > 0) xp = *(const float4*)(x + e - D_DIM);
    float4 m = *(const float4*)(tm + d);
    ushort4 r;
    r.x = f2bf(xc.x * m.x + xp.x * (1.f - m.x));
    r.y = f2bf(xc.y * m.y + xp.y * (1.f - m.y));
    r.z = f2bf(xc.z * m.z + xp.z * (1.f - m.z));
    r.w = f2bf(xc.w * m.w + xp.w * (1.f - m.w));
    *(ushort4*)(o + e) = r;
}

// fused: one x read -> xk, xv, xr  (used when workspace permits)
__global__ void mixall(const float* __restrict__ x,
                       const float* __restrict__ mk, const float* __restrict__ mv,
                       const float* __restrict__ mr,
                       ushort* __restrict__ xk, ushort* __restrict__ xv,
                       ushort* __restrict__ xr) {
    size_t gid = (size_t)blockIdx.x * 256 + threadIdx.x;
    size_t e = gid * 4;
    int d = (int)(e & (D_DIM - 1));
    int t = (int)((e >> 10) & (T_DIM - 1));
    float4 xc = *(const float4*)(x + e);
    float4 xp = make_float4(0.f, 0.f, 0.f, 0.f);
    if (t > 0) xp = *(const float4*)(x + e - D_DIM);
    float4 a = *(const float4*)(mk + d);
    float4 b = *(const float4*)(mv + d);
    float4 c = *(const float4*)(mr + d);
    ushort4 ok, ov, orr;
    ok.x = f2bf(xc.x * a.x + xp.x * (1.f - a.x));
    ok.y = f2bf(xc.y * a.y + xp.y * (1.f - a.y));
    ok.z = f2bf(xc.z * a.z + xp.z * (1.f - a.z));
    ok.w = f2bf(xc.w * a.w + xp.w * (1.f - a.w));
    ov.x = f2bf(xc.x * b.x + xp.x * (1.f - b.x));
    ov.y = f2bf(xc.y * b.y + xp.y * (1.f - b.y));
    ov.z = f2bf(xc.z * b.z + xp.z * (1.f - b.z));
    ov.w = f2bf(xc.w * b.w + xp.w * (1.f - b.w));
    orr.x = f2bf(xc.x * c.x + xp.x * (1.f - c.x));
    orr.y = f2bf(xc.y * c.y + xp.y * (1.f - c.y));
    orr.z = f2bf(xc.z * c.z + xp.z * (1.f - c.z));
    orr.w = f2bf(xc.w * c.w + xp.w * (1.f - c.w));
    *(ushort4*)(xk + e) = ok;
    *(ushort4*)(xv + e) = ov;
    *(ushort4*)(xr + e) = orr;
}

// ---------------- bf16 GEMM: C[M,N] = A[M,K] * B[N,K]^T ----------------------
// T1 XCD swizzle (nwg=1024 % 8 == 0 -> simple bijective form).
// bf16-out path stages C through LDS for full-line coalesced writes.
template <int OUTF32>
__global__ void __launch_bounds__(256)
gemm_bt(const ushort* __restrict__ A0, const ushort* __restrict__ B0,
        void* __restrict__ Cv, size_t sA, size_t sB, size_t sC) {
    constexpr int K = GEMM_K, N = GEMM_N;
    __shared__ ushort As[128 * 32];
    __shared__ ushort Bs[128 * 32];
    const int z = blockIdx.z;
    const ushort* A = A0 + (size_t)z * sA;
    const ushort* Bw = B0 + (size_t)z * sB;

    // XCD-aware swizzle: hw xcd = id%8; give each XCD 128 consecutive tiles
    const int id = blockIdx.y * 8 + blockIdx.x;          // nwg = 1024
    const int L = (id & 7) * 128 + (id >> 3);
    const int bx = L & 7, by = L >> 3;

    const int tid = threadIdx.x;
    const int wid = tid >> 6, lane = tid & 63;
    const int wr = wid >> 1, wc = wid & 1;

    const ushort* Ab = A + (size_t)by * 128 * K;
    const ushort* Bb = Bw + (size_t)bx * 128 * K;
    const ushort* ga = Ab + (size_t)(tid >> 2) * K + ((tid & 3) << 3);
    const ushort* gb = Bb + (size_t)(tid >> 2) * K + ((tid & 3) << 3);
    ushort* lA0 = &As[wid * 512];
    ushort* lA1 = &As[2048 + wid * 512];
    ushort* lB0 = &Bs[wid * 512];
    ushort* lB1 = &Bs[2048 + wid * 512];
    const size_t rstep = (size_t)64 * K;

    f32x4 acc[4][4] = {};
    const int frow = lane & 15;
    const int kgrp = (lane >> 4) << 3;

    for (int kt = 0; kt < K; kt += 32) {
        __syncthreads();
        gload16(ga + kt, lA0);
        gload16(ga + kt + rstep, lA1);
        gload16(gb + kt, lB0);
        gload16(gb + kt + rstep, lB1);
        __syncthreads();
        bf16x8 af[4], bfr[4];
#pragma unroll
        for (int m = 0; m < 4; ++m)
            af[m] = *(const bf16x8*)&As[(wr * 64 + m * 16 + frow) * 32 + kgrp];
#pragma unroll
        for (int n = 0; n < 4; ++n)
            bfr[n] = *(const bf16x8*)&Bs[(wc * 64 + n * 16 + frow) * 32 + kgrp];
#pragma unroll
        for (int m = 0; m < 4; ++m)
#pragma unroll
            for (int n = 0; n < 4; ++n)
                acc[m][n] = __builtin_amdgcn_mfma_f32_16x16x32_bf16(
                    af[m], bfr[n], acc[m][n], 0, 0, 0);
    }

    // C/D layout: col = lane&15, row = (lane>>4)*4 + reg  [m89/m91]
    const int rsub = (lane >> 4) << 2;
    if (OUTF32) {
        float* C = (float*)Cv + (size_t)z * sC;
        const int col = bx * 128 + wc * 64 + frow;
        const int row0 = by * 128 + wr * 64 + rsub;
#pragma unroll
        for (int m = 0; m < 4; ++m)
#pragma unroll
            for (int n = 0; n < 4; ++n)
#pragma unroll
                for (int r = 0; r < 4; ++r)
                    C[(size_t)(row0 + m * 16 + r) * N + col + n * 16] = acc[m][n][r];
    } else {
        // chunked LDS epilogue: 4 x (32 rows x 128 cols) through As (8 KB)
        ushort* C = (ushort*)Cv + (size_t)z * sC;
        ushort* Cs = As;
        const int gRow0 = by * 128, gCol0 = bx * 128;
#pragma unroll
        for (int ch = 0; ch < 4; ++ch) {
            __syncthreads();               // prev chunk stored / K-loop reads done
            if ((ch >> 1) == wr) {
                const int mb = (ch & 1) << 1;
#pragma unroll
                for (int mm = 0; mm < 2; ++mm)
#pragma unroll
                    for (int n = 0; n < 4; ++n)
#pragma unroll
                        for (int r = 0; r < 4; ++r) {
                            int lr = ((mb + mm) & 1) * 16 + rsub + r;   // 0..31
                            int lc = wc * 64 + n * 16 + frow;
                            Cs[lr * 128 + lc] = f2bf(acc[mb + mm][n][r]);
                        }
            }
            __syncthreads();
            // 4096 ushorts: thread t stores 2 x 16B, fully coalesced
            const int lr1 = tid >> 4, lc1 = (tid & 15) << 3;
            size_t g1 = (size_t)(gRow0 + ch * 32 + lr1) * N + gCol0 + lc1;
            size_t g2 = (size_t)(gRow0 + ch * 32 + 16 + lr1) * N + gCol0 + lc1;
            *(bf16x8*)(C + g1) = *(const bf16x8*)&Cs[tid << 3];
            *(bf16x8*)(C + g2) = *(const bf16x8*)&Cs[2048 + (tid << 3)];
        }
    }
}

// ---------------- WKV blocked scan (bf16 k,v,r), 4 channels/thread ----------
__global__ void wkv_passA4(const ushort* __restrict__ k, const ushort* __restrict__ v,
                           const float* __restrict__ w_, float* __restrict__ m_arr,
                           float* __restrict__ s_arr) {
    int gid = blockIdx.x * 256 + threadIdx.x;   // [0, 65536)
    int d4 = gid & 255;                          // d = 4*d4
    int b = (gid >> 8) & 3;
    int c = gid >> 10;
    float4 w4 = *(const float4*)(w_ + d4 * 4);
    size_t base = ((size_t)(b * T_DIM + c * CHL)) * D_DIM + d4 * 4;
    float m0 = -1e30f, m1 = -1e30f, m2 = -1e30f, m3 = -1e30f;
    float s0 = 0.f, s1 = 0.f, s2 = 0.f, s3 = 0.f;
#pragma unroll 2
    for (int i = 0; i < CHL; ++i) {
        ushort4 k4 = *(const ushort4*)(k + base + (size_t)i * D_DIM);
        ushort4 v4 = *(const ushort4*)(v + base + (size_t)i * D_DIM);
        float cw = (float)(CHL - 1 - i);
        float e0 = bf2f(k4.x) + cw * w4.x, e1 = bf2f(k4.y) + cw * w4.y;
        float e2 = bf2f(k4.z) + cw * w4.z, e3 = bf2f(k4.w) + cw * w4.w;
        float n0 = fmaxf(m0, e0), n1 = fmaxf(m1, e1);
        float n2 = fmaxf(m2, e2), n3 = fmaxf(m3, e3);
        s0 = s0 * __expf(fmaxf(m0 - n0, -30.f)) + __expf(fmaxf(e0 - n0, -30.f)) * bf2f(v4.x);
        s1 = s1 * __expf(fmaxf(m1 - n1, -30.f)) + __expf(fmaxf(e1 - n1, -30.f)) * bf2f(v4.y);
        s2 = s2 * __expf(fmaxf(m2 - n2, -30.f)) + __expf(fmaxf(e2 - n2, -30.f)) * bf2f(v4.z);
        s3 = s3 * __expf(fmaxf(m3 - n3, -30.f)) + __expf(fmaxf(e3 - n3, -30.f)) * bf2f(v4.w);
        m0 = n0; m1 = n1; m2 = n2; m3 = n3;
    }
    int idx = ((c * B_DIM + b) << 10) + d4 * 4;
    *(float4*)(m_arr + idx) = make_float4(m0, m1, m2, m3);
    *(float4*)(s_arr + idx) = make_float4(s0, s1, s2, s3);
}

__global__ void wkv_passB(const float* __restrict__ m_arr, const float* __restrict__ s_arr,
                          const float* __restrict__ w_, float* __restrict__ pin,
                          float* __restrict__ qin) {
    int gid = blockIdx.x * 256 + threadIdx.x;   // b*D + d -> 4096
    int d = gid & 1023;
    int b = gid >> 10;
    float w = w_[d];
    float Lw = (float)CHL * w;
    float p = -1e30f, q = 0.f;
    for (int c = 0; c < NCH; ++c) {
        int idx = ((c * B_DIM + b) << 10) | d;
        pin[idx] = p; qin[idx] = q;
        float mc = m_arr[idx], sc = s_arr[idx];
        float pn = fmaxf(p + Lw, mc);
        q = __expf(fmaxf(p + Lw - pn, -30.f)) * q +
            __expf(fmaxf(mc - pn, -30.f)) * sc;
        p = pn;
    }
}

// Pass C: exact reference step from chunk's incoming state; fused sigmoid(r)*wkv
__global__ void wkv_passC4(const ushort* __restrict__ k, const ushort* __restrict__ v,
                           const ushort* __restrict__ r, const float* __restrict__ w_,
                           const float* __restrict__ u_, const float* __restrict__ pin,
                           const float* __restrict__ qin, ushort* __restrict__ y) {
    int gid = blockIdx.x * 256 + threadIdx.x;   // [0, 65536)
    int d4 = gid & 255;
    int b = (gid >> 8) & 3;
    int c = gid >> 10;
    float4 w4 = *(const float4*)(w_ + d4 * 4);
    float4 u4 = *(const float4*)(u_ + d4 * 4);
    int sidx = ((c * B_DIM + b) << 10) + d4 * 4;
    float4 p4 = *(const float4*)(pin + sidx);
    float4 q4 = *(const float4*)(qin + sidx);
    float p0 = p4.x, p1 = p4.y, p2 = p4.z, p3 = p4.w;
    float q0 = q4.x, q1 = q4.y, q2 = q4.z, q3 = q4.w;
    size_t base = ((size_t)(b * T_DIM + c * CHL)) * D_DIM + d4 * 4;
#pragma unroll 2
    for (int i = 0; i < CHL; ++i) {
        ushort4 k4 = *(const ushort4*)(k + base);
        ushort4 v4 = *(const ushort4*)(v + base);
        ushort4 r4 = *(const ushort4*)(r + base);
        ushort4 o;
#define WKV_CH(P, Q, KK, VV, RR, W, U, OUT)                                   \
        {                                                                     \
            float kk = bf2f(KK), vv = bf2f(VV), rr = bf2f(RR);                \
            float uk = (U) + kk;                                              \
            float np = fmaxf(P, uk);                                          \
            float so = __expf(fmaxf(P - np, -30.f));                          \
            float sc = __expf(fmaxf(uk - np, -30.f));                         \
            float wkv = (so * Q + sc * vv) / (so + sc + 1e-9f);               \
            float np2 = fmaxf(P + (W), kk);                                   \
            float sp = __expf(fmaxf(P + (W) - np2, -30.f));                   \
            float sn = __expf(fmaxf(kk - np2, -30.f));                        \
            Q = sp * Q + sn * vv;                                             \
            P = np2;                                                          \
            float sig = 1.f / (1.f + __expf(-rr));                            \
            OUT = f2bf(sig * wkv);                                            \
        }
        WKV_CH(p0, q0, k4.x, v4.x, r4.x, w4.x, u4.x, o.x)
        WKV_CH(p1, q1, k4.y, v4.y, r4.y, w4.y, u4.y, o.y)
        WKV_CH(p2, q2, k4.z, v4.z, r4.z, w4.z, u4.z, o.z)
        WKV_CH(p3, q3, k4.w, v4.w, r4.w, w4.w, u4.w, o.w)
#undef WKV_CH
        *(ushort4*)(y + base) = o;
        base += D_DIM;
    }
}

// ---------------- launch -----------------------------------------------------
extern "C" void kernel_launch(void* const* d_in, const int* in_sizes, int n_in,
                              void* d_out, int out_size, void* d_ws, size_t ws_size,
                              hipStream_t stream) {
    (void)in_sizes; (void)n_in; (void)out_size;
    const float* x  = (const float*)d_in[0];
    const float* mk = (const float*)d_in[1];
    const float* mv = (const float*)d_in[2];
    const float* mr = (const float*)d_in[3];
    const float* Wk = (const float*)d_in[4];
    const float* Wv = (const float*)d_in[5];
    const float* Wr = (const float*)d_in[6];
    const float* Wo = (const float*)d_in[7];
    const float* td = (const float*)d_in[8];
    const float* tf = (const float*)d_in[9];

    const size_t MD = (size_t)M_DIM * D_DIM;         // 16,777,216
    const size_t DD = (size_t)D_DIM * D_DIM;         // 1,048,576
    const size_t CHN = (size_t)B_DIM * D_DIM * NCH;  // 262,144

    // fused layout: wcat + xcat[3MD] + kvr[3MD] + scan scratch  (~214 MB)
    size_t need_big = (4 * DD + 6 * MD) * 2 + 4 * CHN * 4;
    // fallback layout (known-safe 147 MB from round 2/4)
    size_t need_small = (4 * DD + 4 * MD) * 2 + 4 * CHN * 4;
    if (ws_size < need_small) return;

    dim3 g1(8, 128, 1), g3(8, 128, 3);

    if (ws_size >= need_big) {
        ushort* wcat = (ushort*)d_ws;
        ushort* xcat = wcat + 4 * DD;          // xk | xv | xr
        ushort* kvr  = xcat + 3 * MD;          // k | v | r
        float* m_arr = (float*)(kvr + 3 * MD);
        float* s_arr = m_arr + CHN;
        float* pin   = s_arr + CHN;
        float* qin   = pin + CHN;
        ushort* ybuf = xcat;                   // reuse xk after GEMMs

        convw<<<4096, 256, 0, stream>>>(Wk, Wv, Wr, Wo, wcat);
        mixall<<<16384, 256, 0, stream>>>(x, mk, mv, mr,
                                          xcat, xcat + MD, xcat + 2 * MD);
        gemm_bt<0><<<g3, 256, 0, stream>>>(xcat, wcat, kvr, MD, DD, MD);
        wkv_passA4<<<256, 256, 0, stream>>>(kvr, kvr + MD, td, m_arr, s_arr);
        wkv_passB<<<16, 256, 0, stream>>>(m_arr, s_arr, td, pin, qin);
        wkv_passC4<<<256, 256, 0, stream>>>(kvr, kvr + MD, kvr + 2 * MD,
                                            td, tf, pin, qin, ybuf);
        gemm_bt<1><<<g1, 256, 0, stream>>>(ybuf, wcat + 3 * DD, d_out, 0, 0, 0);
    } else {
        ushort* wcat = (ushort*)d_ws;
        ushort* kbuf = wcat + 4 * DD;
        ushort* vbuf = kbuf + MD;
        ushort* rbuf = vbuf + MD;
        ushort* xbuf = rbuf + MD;
        float* m_arr = (float*)(xbuf + MD);
        float* s_arr = m_arr + CHN;
        float* pin   = s_arr + CHN;
        float* qin   = pin + CHN;

        convw<<<4096, 256, 0, stream>>>(Wk, Wv, Wr, Wo, wcat);
        mixz<<<16384, 256, 0, stream>>>(x, mk, xbuf);
        gemm_bt<0><<<g1, 256, 0, stream>>>(xbuf, wcat, kbuf, 0, 0, 0);
        mixz<<<16384, 256, 0, stream>>>(x, mv, xbuf);
        gemm_bt<0><<<g1, 256, 0, stream>>>(xbuf, wcat + DD, vbuf, 0, 0, 0);
        mixz<<<16384, 256, 0, stream>>>(x, mr, xbuf);
        gemm_bt<0><<<g1, 256, 0, stream>>>(xbuf, wcat + 2 * DD, rbuf, 0, 0, 0);
        wkv_passA4<<<256, 256, 0, stream>>>(kbuf, vbuf, td, m_arr, s_arr);
        wkv_passB<<<16, 256, 0, stream>>>(m_arr, s_arr, td, pin, qin);
        wkv_passC4<<<256, 256, 0, stream>>>(kbuf, vbuf, rbuf, td, tf, pin, qin, xbuf);
        gemm_bt<1><<<g1, 256, 0, stream>>>(xbuf, wcat + 3 * DD, d_out, 0, 0, 0);
    }
}

// Round 6
// 429.777 us; speedup vs baseline: 1.0964x; 1.0364x over previous
//
#include <hip/hip_runtime.h>
#include <stdint.h>

// Problem constants: B=4, T=4096, D=1024
#define D_DIM 1024
#define T_DIM 4096
#define B_DIM 4
#define M_DIM (B_DIM * T_DIM)   // 16384 rows
#define NCH 64                  // scan chunks
#define CHL 64                  // chunk length
#define GEMM_N 1024
#define GEMM_K 1024

typedef short bf16x8 __attribute__((ext_vector_type(8)));
typedef float f32x4 __attribute__((ext_vector_type(4)));

__device__ __forceinline__ ushort f2bf(float f) {
    union { float f; uint32_t u; } x; x.f = f;
    uint32_t r = x.u + 0x7fffu + ((x.u >> 16) & 1u);   // RNE
    return (ushort)(r >> 16);
}
__device__ __forceinline__ float bf2f(ushort u) {
    union { uint32_t u; float f; } x; x.u = (uint32_t)u << 16; return x.f;
}

__device__ __forceinline__ void gload16(const ushort* g, ushort* l) {
    __builtin_amdgcn_global_load_lds(
        (const __attribute__((address_space(1))) void*)g,
        (__attribute__((address_space(3))) void*)l, 16, 0, 0);
}

// ---------------- weight fp32 -> bf16 (Wk,Wv,Wr,Wo concatenated) -------------
__global__ void convw(const float* __restrict__ w0, const float* __restrict__ w1,
                      const float* __restrict__ w2, const float* __restrict__ w3,
                      ushort* __restrict__ out) {
    int i = blockIdx.x * 256 + threadIdx.x;        // 1M float4 groups
    int sel = i >> 18;
    const float* src = sel == 0 ? w0 : sel == 1 ? w1 : sel == 2 ? w2 : w3;
    int off = (i & 0x3ffff) << 2;
    float4 f = *(const float4*)(src + off);
    ushort4 o; o.x = f2bf(f.x); o.y = f2bf(f.y); o.z = f2bf(f.z); o.w = f2bf(f.w);
    *(ushort4*)(out + (size_t)i * 4) = o;
}

// ---------------- token shift + time-mix -------------------------------------
__global__ void mixz(const float* __restrict__ x, const float* __restrict__ tm,
                     ushort* __restrict__ o) {
    size_t gid = (size_t)blockIdx.x * 256 + threadIdx.x;
    size_t e = gid * 4;
    int d = (int)(e & (D_DIM - 1));
    int t = (int)((e >> 10) & (T_DIM - 1));
    float4 xc = *(const float4*)(x + e);
    float4 xp = make_float4(0.f, 0.f, 0.f, 0.f);
    if (t > 0) xp = *(const float4*)(x + e - D_DIM);
    float4 m = *(const float4*)(tm + d);
    ushort4 r;
    r.x = f2bf(xc.x * m.x + xp.x * (1.f - m.x));
    r.y = f2bf(xc.y * m.y + xp.y * (1.f - m.y));
    r.z = f2bf(xc.z * m.z + xp.z * (1.f - m.z));
    r.w = f2bf(xc.w * m.w + xp.w * (1.f - m.w));
    *(ushort4*)(o + e) = r;
}

// fused: one x read -> xk, xv, xr
__global__ void mixall(const float* __restrict__ x,
                       const float* __restrict__ mk, const float* __restrict__ mv,
                       const float* __restrict__ mr,
                       ushort* __restrict__ xk, ushort* __restrict__ xv,
                       ushort* __restrict__ xr) {
    size_t gid = (size_t)blockIdx.x * 256 + threadIdx.x;
    size_t e = gid * 4;
    int d = (int)(e & (D_DIM - 1));
    int t = (int)((e >> 10) & (T_DIM - 1));
    float4 xc = *(const float4*)(x + e);
    float4 xp = make_float4(0.f, 0.f, 0.f, 0.f);
    if (t > 0) xp = *(const float4*)(x + e - D_DIM);
    float4 a = *(const float4*)(mk + d);
    float4 b = *(const float4*)(mv + d);
    float4 c = *(const float4*)(mr + d);
    ushort4 ok, ov, orr;
    ok.x = f2bf(xc.x * a.x + xp.x * (1.f - a.x));
    ok.y = f2bf(xc.y * a.y + xp.y * (1.f - a.y));
    ok.z = f2bf(xc.z * a.z + xp.z * (1.f - a.z));
    ok.w = f2bf(xc.w * a.w + xp.w * (1.f - a.w));
    ov.x = f2bf(xc.x * b.x + xp.x * (1.f - b.x));
    ov.y = f2bf(xc.y * b.y + xp.y * (1.f - b.y));
    ov.z = f2bf(xc.z * b.z + xp.z * (1.f - b.z));
    ov.w = f2bf(xc.w * b.w + xp.w * (1.f - b.w));
    orr.x = f2bf(xc.x * c.x + xp.x * (1.f - c.x));
    orr.y = f2bf(xc.y * c.y + xp.y * (1.f - c.y));
    orr.z = f2bf(xc.z * c.z + xp.z * (1.f - c.z));
    orr.w = f2bf(xc.w * c.w + xp.w * (1.f - c.w));
    *(ushort4*)(xk + e) = ok;
    *(ushort4*)(xv + e) = ov;
    *(ushort4*)(xr + e) = orr;
}

// ---------------- bf16 GEMM: C[M,N] = A[M,K] * B[N,K]^T ----------------------
// T1 XCD swizzle + T3/T4 minimum-2-phase pipeline: double-buffered LDS,
// stage(t+1) issued before compute(t), raw s_barrier (no compiler vmcnt(0)
// drain), per-wave counted s_waitcnt vmcnt(4). LDS-staged coalesced C-writes.
template <int OUTF32>
__global__ void __launch_bounds__(256)
gemm_bt(const ushort* __restrict__ A0, const ushort* __restrict__ B0,
        void* __restrict__ Cv, size_t sA, size_t sB, size_t sC) {
    constexpr int K = GEMM_K, N = GEMM_N;
    __shared__ ushort shm[16384];        // 32 KB: A0|A1|B0|B1, 8 KB each
    const int z = blockIdx.z;
    const ushort* A = A0 + (size_t)z * sA;
    const ushort* Bw = B0 + (size_t)z * sB;

    // XCD-aware swizzle: hw xcd = linear%8 = blockIdx.x; 128 consecutive tiles/XCD
    const int id = blockIdx.y * 8 + blockIdx.x;          // nwg = 1024
    const int L = (id & 7) * 128 + (id >> 3);
    const int bx = L & 7, by = L >> 3;

    const int tid = threadIdx.x;
    const int wid = tid >> 6, lane = tid & 63;
    const int wr = wid >> 1, wc = wid & 1;

    const ushort* Ab = A + (size_t)by * 128 * K;
    const ushort* Bb = Bw + (size_t)bx * 128 * K;
    const ushort* ga = Ab + (size_t)(tid >> 2) * K + ((tid & 3) << 3);
    const ushort* gb = Bb + (size_t)(tid >> 2) * K + ((tid & 3) << 3);
    const size_t rstep = (size_t)64 * K;

    f32x4 acc[4][4] = {};
    const int frow = lane & 15;
    const int kgrp = (lane >> 4) << 3;

    // stage K-tile starting at column kt into buffer b (4 gloads, async)
    auto stage = [&](int kt, int b) {
        ushort* la = &shm[b * 4096 + wid * 512];
        ushort* lb = &shm[8192 + b * 4096 + wid * 512];
        gload16(ga + kt, la);
        gload16(ga + kt + rstep, la + 2048);
        gload16(gb + kt, lb);
        gload16(gb + kt + rstep, lb + 2048);
    };

    stage(0, 0);
    for (int t = 0; t < 32; ++t) {
        const int cur = t & 1;
        if (t < 31) {
            stage((t + 1) << 5, cur ^ 1);                 // prefetch next tile
            asm volatile("s_waitcnt vmcnt(4)" ::: "memory");  // own tile-t loads done
        } else {
            asm volatile("s_waitcnt vmcnt(0)" ::: "memory");
        }
        __builtin_amdgcn_s_barrier();     // all waves' tile-t loads visible
        const ushort* As = &shm[cur * 4096];
        const ushort* Bs = &shm[8192 + cur * 4096];
        bf16x8 af[4], bfr[4];
#pragma unroll
        for (int m = 0; m < 4; ++m)
            af[m] = *(const bf16x8*)&As[(wr * 64 + m * 16 + frow) * 32 + kgrp];
#pragma unroll
        for (int n = 0; n < 4; ++n)
            bfr[n] = *(const bf16x8*)&Bs[(wc * 64 + n * 16 + frow) * 32 + kgrp];
#pragma unroll
        for (int m = 0; m < 4; ++m)
#pragma unroll
            for (int n = 0; n < 4; ++n)
                acc[m][n] = __builtin_amdgcn_mfma_f32_16x16x32_bf16(
                    af[m], bfr[n], acc[m][n], 0, 0, 0);
        __builtin_amdgcn_s_barrier();     // reads done before next stage overwrites
    }

    // C/D layout: col = lane&15, row = (lane>>4)*4 + reg  [m89/m91]
    // Chunked LDS epilogue: 4 x (32 rows x 128 cols), fully coalesced stores.
    const int rsub = (lane >> 4) << 2;
    const int gRow0 = by * 128, gCol0 = bx * 128;
    if (OUTF32) {
        float* C = (float*)Cv + (size_t)z * sC;
        float* Cs = (float*)shm;          // 16 KB chunk: 32 x 128 f32
#pragma unroll
        for (int ch = 0; ch < 4; ++ch) {
            __syncthreads();
            if ((ch >> 1) == wr) {
                const int mb = (ch & 1) << 1;
#pragma unroll
                for (int mm = 0; mm < 2; ++mm)
#pragma unroll
                    for (int n = 0; n < 4; ++n)
#pragma unroll
                        for (int r = 0; r < 4; ++r)
                            Cs[(mm * 16 + rsub + r) * 128 + wc * 64 + n * 16 + frow]
                                = acc[mb + mm][n][r];
            }
            __syncthreads();
#pragma unroll
            for (int pass = 0; pass < 4; ++pass) {
                int lr = pass * 8 + (tid >> 5);
                int lc = (tid & 31) << 2;
                *(float4*)(C + (size_t)(gRow0 + ch * 32 + lr) * N + gCol0 + lc)
                    = *(const float4*)&Cs[lr * 128 + lc];
            }
        }
    } else {
        ushort* C = (ushort*)Cv + (size_t)z * sC;
        ushort* Cs = shm;                 // 8 KB chunk: 32 x 128 bf16
#pragma unroll
        for (int ch = 0; ch < 4; ++ch) {
            __syncthreads();
            if ((ch >> 1) == wr) {
                const int mb = (ch & 1) << 1;
#pragma unroll
                for (int mm = 0; mm < 2; ++mm)
#pragma unroll
                    for (int n = 0; n < 4; ++n)
#pragma unroll
                        for (int r = 0; r < 4; ++r)
                            Cs[(mm * 16 + rsub + r) * 128 + wc * 64 + n * 16 + frow]
                                = f2bf(acc[mb + mm][n][r]);
            }
            __syncthreads();
            const int lr1 = tid >> 4, lc1 = (tid & 15) << 3;
            size_t g1 = (size_t)(gRow0 + ch * 32 + lr1) * N + gCol0 + lc1;
            size_t g2 = (size_t)(gRow0 + ch * 32 + 16 + lr1) * N + gCol0 + lc1;
            *(bf16x8*)(C + g1) = *(const bf16x8*)&Cs[tid << 3];
            *(bf16x8*)(C + g2) = *(const bf16x8*)&Cs[2048 + (tid << 3)];
        }
    }
}

// ---------------- WKV blocked scan (bf16 k,v,r), 4 channels/thread ----------
__global__ void wkv_passA4(const ushort* __restrict__ k, const ushort* __restrict__ v,
                           const float* __restrict__ w_, float* __restrict__ m_arr,
                           float* __restrict__ s_arr) {
    int gid = blockIdx.x * 256 + threadIdx.x;   // [0, 65536)
    int d4 = gid & 255;                          // d = 4*d4
    int b = (gid >> 8) & 3;
    int c = gid >> 10;
    float4 w4 = *(const float4*)(w_ + d4 * 4);
    size_t base = ((size_t)(b * T_DIM + c * CHL)) * D_DIM + d4 * 4;
    float m0 = -1e30f, m1 = -1e30f, m2 = -1e30f, m3 = -1e30f;
    float s0 = 0.f, s1 = 0.f, s2 = 0.f, s3 = 0.f;
#pragma unroll 2
    for (int i = 0; i < CHL; ++i) {
        ushort4 k4 = *(const ushort4*)(k + base + (size_t)i * D_DIM);
        ushort4 v4 = *(const ushort4*)(v + base + (size_t)i * D_DIM);
        float cw = (float)(CHL - 1 - i);
        float e0 = bf2f(k4.x) + cw * w4.x, e1 = bf2f(k4.y) + cw * w4.y;
        float e2 = bf2f(k4.z) + cw * w4.z, e3 = bf2f(k4.w) + cw * w4.w;
        float n0 = fmaxf(m0, e0), n1 = fmaxf(m1, e1);
        float n2 = fmaxf(m2, e2), n3 = fmaxf(m3, e3);
        s0 = s0 * __expf(fmaxf(m0 - n0, -30.f)) + __expf(fmaxf(e0 - n0, -30.f)) * bf2f(v4.x);
        s1 = s1 * __expf(fmaxf(m1 - n1, -30.f)) + __expf(fmaxf(e1 - n1, -30.f)) * bf2f(v4.y);
        s2 = s2 * __expf(fmaxf(m2 - n2, -30.f)) + __expf(fmaxf(e2 - n2, -30.f)) * bf2f(v4.z);
        s3 = s3 * __expf(fmaxf(m3 - n3, -30.f)) + __expf(fmaxf(e3 - n3, -30.f)) * bf2f(v4.w);
        m0 = n0; m1 = n1; m2 = n2; m3 = n3;
    }
    int idx = ((c * B_DIM + b) << 10) + d4 * 4;
    *(float4*)(m_arr + idx) = make_float4(m0, m1, m2, m3);
    *(float4*)(s_arr + idx) = make_float4(s0, s1, s2, s3);
}

__global__ void wkv_passB(const float* __restrict__ m_arr, const float* __restrict__ s_arr,
                          const float* __restrict__ w_, float* __restrict__ pin,
                          float* __restrict__ qin) {
    int gid = blockIdx.x * 256 + threadIdx.x;   // b*D + d -> 4096
    int d = gid & 1023;
    int b = gid >> 10;
    float w = w_[d];
    float Lw = (float)CHL * w;
    float p = -1e30f, q = 0.f;
    for (int c = 0; c < NCH; ++c) {
        int idx = ((c * B_DIM + b) << 10) | d;
        pin[idx] = p; qin[idx] = q;
        float mc = m_arr[idx], sc = s_arr[idx];
        float pn = fmaxf(p + Lw, mc);
        q = __expf(fmaxf(p + Lw - pn, -30.f)) * q +
            __expf(fmaxf(mc - pn, -30.f)) * sc;
        p = pn;
    }
}

// Pass C: exact reference step from chunk's incoming state; fused sigmoid(r)*wkv
__global__ void wkv_passC4(const ushort* __restrict__ k, const ushort* __restrict__ v,
                           const ushort* __restrict__ r, const float* __restrict__ w_,
                           const float* __restrict__ u_, const float* __restrict__ pin,
                           const float* __restrict__ qin, ushort* __restrict__ y) {
    int gid = blockIdx.x * 256 + threadIdx.x;   // [0, 65536)
    int d4 = gid & 255;
    int b = (gid >> 8) & 3;
    int c = gid >> 10;
    float4 w4 = *(const float4*)(w_ + d4 * 4);
    float4 u4 = *(const float4*)(u_ + d4 * 4);
    int sidx = ((c * B_DIM + b) << 10) + d4 * 4;
    float4 p4 = *(const float4*)(pin + sidx);
    float4 q4 = *(const float4*)(qin + sidx);
    float p0 = p4.x, p1 = p4.y, p2 = p4.z, p3 = p4.w;
    float q0 = q4.x, q1 = q4.y, q2 = q4.z, q3 = q4.w;
    size_t base = ((size_t)(b * T_DIM + c * CHL)) * D_DIM + d4 * 4;
#pragma unroll 2
    for (int i = 0; i < CHL; ++i) {
        ushort4 k4 = *(const ushort4*)(k + base);
        ushort4 v4 = *(const ushort4*)(v + base);
        ushort4 r4 = *(const ushort4*)(r + base);
        ushort4 o;
#define WKV_CH(P, Q, KK, VV, RR, W, U, OUT)                                   \
        {                                                                     \
            float kk = bf2f(KK), vv = bf2f(VV), rr = bf2f(RR);                \
            float uk = (U) + kk;                                              \
            float np = fmaxf(P, uk);                                          \
            float so = __expf(fmaxf(P - np, -30.f));                          \
            float sc = __expf(fmaxf(uk - np, -30.f));                         \
            float wkv = (so * Q + sc * vv) / (so + sc + 1e-9f);               \
            float np2 = fmaxf(P + (W), kk);                                   \
            float sp = __expf(fmaxf(P + (W) - np2, -30.f));                   \
            float sn = __expf(fmaxf(kk - np2, -30.f));                        \
            Q = sp * Q + sn * vv;                                             \
            P = np2;                                                          \
            float sig = 1.f / (1.f + __expf(-rr));                            \
            OUT = f2bf(sig * wkv);                                            \
        }
        WKV_CH(p0, q0, k4.x, v4.x, r4.x, w4.x, u4.x, o.x)
        WKV_CH(p1, q1, k4.y, v4.y, r4.y, w4.y, u4.y, o.y)
        WKV_CH(p2, q2, k4.z, v4.z, r4.z, w4.z, u4.z, o.z)
        WKV_CH(p3, q3, k4.w, v4.w, r4.w, w4.w, u4.w, o.w)
#undef WKV_CH
        *(ushort4*)(y + base) = o;
        base += D_DIM;
    }
}

// ---------------- launch -----------------------------------------------------
extern "C" void kernel_launch(void* const* d_in, const int* in_sizes, int n_in,
                              void* d_out, int out_size, void* d_ws, size_t ws_size,
                              hipStream_t stream) {
    (void)in_sizes; (void)n_in; (void)out_size;
    const float* x  = (const float*)d_in[0];
    const float* mk = (const float*)d_in[1];
    const float* mv = (const float*)d_in[2];
    const float* mr = (const float*)d_in[3];
    const float* Wk = (const float*)d_in[4];
    const float* Wv = (const float*)d_in[5];
    const float* Wr = (const float*)d_in[6];
    const float* Wo = (const float*)d_in[7];
    const float* td = (const float*)d_in[8];
    const float* tf = (const float*)d_in[9];

    const size_t MD = (size_t)M_DIM * D_DIM;         // 16,777,216
    const size_t DD = (size_t)D_DIM * D_DIM;         // 1,048,576
    const size_t CHN = (size_t)B_DIM * D_DIM * NCH;  // 262,144

    size_t need_big = (4 * DD + 6 * MD) * 2 + 4 * CHN * 4;   // ~214 MB (ran in r5)
    size_t need_small = (4 * DD + 4 * MD) * 2 + 4 * CHN * 4; // known-safe 147 MB
    if (ws_size < need_small) return;

    dim3 g1(8, 128, 1), g3(8, 128, 3);

    if (ws_size >= need_big) {
        ushort* wcat = (ushort*)d_ws;
        ushort* xcat = wcat + 4 * DD;          // xk | xv | xr
        ushort* kvr  = xcat + 3 * MD;          // k | v | r
        float* m_arr = (float*)(kvr + 3 * MD);
        float* s_arr = m_arr + CHN;
        float* pin   = s_arr + CHN;
        float* qin   = pin + CHN;
        ushort* ybuf = xcat;                   // reuse xk after GEMMs

        convw<<<4096, 256, 0, stream>>>(Wk, Wv, Wr, Wo, wcat);
        mixall<<<16384, 256, 0, stream>>>(x, mk, mv, mr,
                                          xcat, xcat + MD, xcat + 2 * MD);
        gemm_bt<0><<<g3, 256, 0, stream>>>(xcat, wcat, kvr, MD, DD, MD);
        wkv_passA4<<<256, 256, 0, stream>>>(kvr, kvr + MD, td, m_arr, s_arr);
        wkv_passB<<<16, 256, 0, stream>>>(m_arr, s_arr, td, pin, qin);
        wkv_passC4<<<256, 256, 0, stream>>>(kvr, kvr + MD, kvr + 2 * MD,
                                            td, tf, pin, qin, ybuf);
        gemm_bt<1><<<g1, 256, 0, stream>>>(ybuf, wcat + 3 * DD, d_out, 0, 0, 0);
    } else {
        ushort* wcat = (ushort*)d_ws;
        ushort* kbuf = wcat + 4 * DD;
        ushort* vbuf = kbuf + MD;
        ushort* rbuf = vbuf + MD;
        ushort* xbuf = rbuf + MD;
        float* m_arr = (float*)(xbuf + MD);
        float* s_arr = m_arr + CHN;
        float* pin   = s_arr + CHN;
        float* qin   = pin + CHN;

        convw<<<4096, 256, 0, stream>>>(Wk, Wv, Wr, Wo, wcat);
        mixz<<<16384, 256, 0, stream>>>(x, mk, xbuf);
        gemm_bt<0><<<g1, 256, 0, stream>>>(xbuf, wcat, kbuf, 0, 0, 0);
        mixz<<<16384, 256, 0, stream>>>(x, mv, xbuf);
        gemm_bt<0><<<g1, 256, 0, stream>>>(xbuf, wcat + DD, vbuf, 0, 0, 0);
        mixz<<<16384, 256, 0, stream>>>(x, mr, xbuf);
        gemm_bt<0><<<g1, 256, 0, stream>>>(xbuf, wcat + 2 * DD, rbuf, 0, 0, 0);
        wkv_passA4<<<256, 256, 0, stream>>>(kbuf, vbuf, td, m_arr, s_arr);
        wkv_passB<<<16, 256, 0, stream>>>(m_arr, s_arr, td, pin, qin);
        wkv_passC4<<<256, 256, 0, stream>>>(kbuf, vbuf, rbuf, td, tf, pin, qin, xbuf);
        gemm_bt<1><<<g1, 256, 0, stream>>>(xbuf, wcat + 3 * DD, d_out, 0, 0, 0);
    }
}